// Round 3
// baseline (3169.448 us; speedup 1.0000x reference)
//
#include <hip/hip_runtime.h>
#include <math.h>

#define KNB 24

// ---------------------------------------------------------------- utilities
__global__ void k_zero(double* acc) {
    if (threadIdx.x < 8) acc[threadIdx.x] = 0.0;
}

__global__ void k_iota(int* __restrict__ fi, int G, int tot) {
    int i = blockIdx.x * blockDim.x + threadIdx.x;
    if (i < tot) fi[i] = i % G;
}

// x [B,C,N] -> feats [B,N,C]
__global__ void k_transpose(const float* __restrict__ x, float* __restrict__ feats,
                            int B, int C, int N) {
    int idx = blockIdx.x * blockDim.x + threadIdx.x;
    int tot = B * C * N;
    if (idx >= tot) return;
    int n = idx % N; int t = idx / N; int c = t % C; int b = t / C;
    feats[((size_t)b * N + n) * C + c] = x[idx];
}

// ---------------------------------------------------------------- FPS
// DPP-based full-wave f32 max (result valid in lane 63)
template<int CTRL>
__device__ __forceinline__ float dppmax(float v) {
    int t = __builtin_amdgcn_update_dpp(0, __float_as_int(v), CTRL, 0xf, 0xf, true);
    return fmaxf(v, __int_as_float(t));
}

// one workgroup per batch; dist+xyz register-resident; one barrier per iter;
// winning centroid's coords carried through the LDS key exchange.
template<int NPT, int NWAVE>
__global__ __launch_bounds__(64 * NWAVE) void k_fps_t(const float* __restrict__ xyz,
                                                      int* __restrict__ fi,
                                                      int N, int M) {
#pragma clang fp contract(off)
    const int b = blockIdx.x;
    const int tid = threadIdx.x;
    const int wid = tid >> 6;              // wave id
    const int lane = tid & 63;
    extern __shared__ float smem[];
    // red[2][NWAVE][8]: {dist, idx(bitcast), x, y, z, pad...} per wave, parity dbuf
    float (*red)[NWAVE][8] = (float(*)[NWAVE][8])smem;
    float* px = smem + 2 * NWAVE * 8;
    float* py = px + N;
    float* pz = py + N;

    const float* p = xyz + (size_t)b * N * 3;
    for (int i = tid; i < N; i += 64 * NWAVE) {
        px[i] = p[i*3]; py[i] = p[i*3+1]; pz[i] = p[i*3+2];
    }
    __syncthreads();

    const int base = tid * NPT;
    float rx[NPT], ry[NPT], rz[NPT], dist[NPT];
#pragma unroll
    for (int j = 0; j < NPT; ++j) {
        rx[j] = px[base + j]; ry[j] = py[base + j]; rz[j] = pz[base + j];
        dist[j] = 1e10f;
    }

    int far = 0;
    float cx = px[0], cy = py[0], cz = pz[0];
    for (int it = 0; it < M; ++it) {
        if (tid == 0) fi[b * M + it] = far;          // record carry BEFORE update
        float bv = -1.0f; int bi = 0;
        float bx = 0.0f, by = 0.0f, bz = 0.0f;
#pragma unroll
        for (int j = 0; j < NPT; ++j) {
            float dx = rx[j] - cx, dy = ry[j] - cy, dz = rz[j] - cz;
            float d = (dx*dx + dy*dy) + dz*dz;       // ((d0+d1)+d2), no fma
            float dd = fminf(dist[j], d);
            dist[j] = dd;
            if (dd > bv) { bv = dd; bi = base + j; bx = rx[j]; by = ry[j]; bz = rz[j]; }
        }
        // DPP value-only wave max (all dists >= 0, bound_ctrl zero-fill safe)
        float r = bv;
        r = dppmax<0x111>(r); r = dppmax<0x112>(r);
        r = dppmax<0x114>(r); r = dppmax<0x118>(r);
        r = dppmax<0x142>(r); r = dppmax<0x143>(r);
        float wmax = __int_as_float(__builtin_amdgcn_readlane(__float_as_int(r), 63));
        // lowest lane holding the max = smallest global index (per-lane first-max kept)
        unsigned long long mask = __ballot(bv == wmax);
        int src = __builtin_ctzll(mask);
        int   wbi = __builtin_amdgcn_readlane(bi, src);
        float wbx = __int_as_float(__builtin_amdgcn_readlane(__float_as_int(bx), src));
        float wby = __int_as_float(__builtin_amdgcn_readlane(__float_as_int(by), src));
        float wbz = __int_as_float(__builtin_amdgcn_readlane(__float_as_int(bz), src));
        if (lane == 0) {
            float* s = &red[it & 1][wid][0];
            *(float4*)s = make_float4(wmax, __int_as_float(wbi), wbx, wby);
            s[4] = wbz;
        }
        __syncthreads();
        // every thread reduces the NWAVE slots redundantly
        {
            const float* s0 = &red[it & 1][0][0];
            float4 c0 = *(const float4*)s0;
            float bd = c0.x; int bidx = __float_as_int(c0.y);
            float x = c0.z, y = c0.w, z = s0[4];
#pragma unroll
            for (int w = 1; w < NWAVE; ++w) {
                const float* s = &red[it & 1][w][0];
                float4 c = *(const float4*)s;
                float czv = s[4];
                int ci = __float_as_int(c.y);
                bool better = (c.x > bd) || (c.x == bd && ci < bidx);
                if (better) { bd = c.x; bidx = ci; x = c.z; y = c.w; z = czv; }
            }
            far = bidx; cx = x; cy = y; cz = z;
        }
    }
}

// ---------------------------------------------------------------- gather centers
__global__ void k_gather(const float* __restrict__ xyz, const float* __restrict__ feats,
                         const int* __restrict__ fi, float* __restrict__ lc_xyz,
                         float* __restrict__ lc_x, int B, int N, int G, int C) {
    int i = blockIdx.x * blockDim.x + threadIdx.x;
    int tot = B * G * (C + 3);
    if (i >= tot) return;
    int c = i % (C + 3); int bg = i / (C + 3);
    int b = bg / G;
    int idx = fi[bg];
    if (c < 3) lc_xyz[(size_t)bg * 3 + c] = xyz[((size_t)b * N + idx) * 3 + c];
    else       lc_x[(size_t)bg * C + (c - 3)] = feats[((size_t)b * N + idx) * C + (c - 3)];
}

// ---------------------------------------------------------------- kNN (24 smallest, ties->lower idx)
__global__ __launch_bounds__(256) void k_knn(const float* __restrict__ xyz,
                                             const float* __restrict__ lc_xyz,
                                             int* __restrict__ ki, int B, int N, int G) {
#pragma clang fp contract(off)
    int bg = blockIdx.x; int b = bg / G;
    extern __shared__ float sd[];
    float* rv = sd + N; int* ri = (int*)(rv + 8);
    const float* p = xyz + (size_t)b * N * 3;
    float cx = lc_xyz[(size_t)bg*3], cy = lc_xyz[(size_t)bg*3+1], cz = lc_xyz[(size_t)bg*3+2];
    float cc = (cx*cx + cy*cy) + cz*cz;
    for (int i = threadIdx.x; i < N; i += blockDim.x) {
        float x0 = p[i*3], x1 = p[i*3+1], x2 = p[i*3+2];
        float xx = (x0*x0 + x1*x1) + x2*x2;
        float dt = (cx*x0 + cy*x1) + cz*x2;
        sd[i] = (cc - 2.0f*dt) + xx;          // (cc - 2dot) + xx, matches ref assoc
    }
    __syncthreads();
    for (int kk = 0; kk < KNB; ++kk) {
        float bv = 1e30f; int bi = N;
        for (int i = threadIdx.x; i < N; i += blockDim.x) {
            float v = sd[i];
            if (v < bv) { bv = v; bi = i; }   // i increasing -> first-min kept
        }
        for (int off = 32; off > 0; off >>= 1) {
            float ov = __shfl_down(bv, off); int oi = __shfl_down(bi, off);
            if (ov < bv || (ov == bv && oi < bi)) { bv = ov; bi = oi; }
        }
        int wid = threadIdx.x >> 6;
        if ((threadIdx.x & 63) == 0) { rv[wid] = bv; ri[wid] = bi; }
        __syncthreads();
        if (threadIdx.x == 0) {
            int nw = blockDim.x >> 6;
            float v = rv[0]; int ii = ri[0];
            for (int w = 1; w < nw; ++w) {
                if (rv[w] < v || (rv[w] == v && ri[w] < ii)) { v = rv[w]; ii = ri[w]; }
            }
            ki[(size_t)bg * KNB + kk] = ii;
            sd[ii] = 1e30f;
        }
        __syncthreads();
    }
}

// ---------------------------------------------------------------- global std reduction (sum, sumsq)
__global__ void k_stdsum(const float* __restrict__ feats, const float* __restrict__ lc,
                         const int* __restrict__ ki, double* __restrict__ acc,
                         int B, int N, int G, int C) {
    size_t tot = (size_t)B * G * KNB * C;
    double s = 0.0, s2 = 0.0;
    size_t stride = (size_t)gridDim.x * blockDim.x;
    for (size_t i = (size_t)blockIdx.x * blockDim.x + threadIdx.x; i < tot; i += stride) {
        int c = (int)(i % C); size_t t = i / C; int k = (int)(t % KNB); size_t bg = t / KNB;
        int b = (int)(bg / G);
        int idx = ki[bg * KNB + k];
        float d = feats[((size_t)b * N + idx) * C + c] - lc[bg * C + c];
        s += (double)d; s2 += (double)d * (double)d;
    }
    for (int off = 32; off > 0; off >>= 1) { s += __shfl_down(s, off); s2 += __shfl_down(s2, off); }
    if ((threadIdx.x & 63) == 0) { atomicAdd(acc, s); atomicAdd(acc + 1, s2); }
}

__global__ void k_finalize(const double* __restrict__ acc, float* __restrict__ inv,
                           double nx, double nz) {
    if (threadIdx.x == 0) {
        double vx = (acc[1] - acc[0] * acc[0] / nx) / (nx - 1.0);
        float sx = sqrtf((float)vx);
        inv[0] = 1.0f / (sx + 1e-5f);
        double vz = (acc[3] - acc[2] * acc[2] / nz) / (nz - 1.0);
        float sz = sqrtf((float)vz);
        inv[1] = 1.0f / (sz + 1e-5f);
    }
}

// ---------------------------------------------------------------- LGA feature + pool (one wg per (b,g))
__global__ __launch_bounds__(256) void k_feature(
    const float* __restrict__ xyz, const float* __restrict__ feats,
    const float* __restrict__ lc_xyz, const float* __restrict__ lc_x,
    const int* __restrict__ ki, const float* __restrict__ Bmat,
    const float* __restrict__ inv, float* __restrict__ pooled,
    int B, int N, int G, int C)
{
    int bg = blockIdx.x; int b = bg / G; int g = bg % G;
    int tid = threadIdx.x;
    int C2 = C >> 1;
    int Cout = 2 * C;
    int F = C / 3;                         // tr_embed F = (2C)/(2*3)
    extern __shared__ float sm[];
    float* t7    = sm;                     // [24][7]
    float* sxyzn = t7 + KNB * 7;           // [24][3]
    int*   kidx  = (int*)(sxyzn + KNB * 3);// [24]
    float* semb  = (float*)(kidx + KNB);   // [24][C]

    float invx = inv[0], invz = inv[1];
    float l0 = lc_xyz[(size_t)bg*3], l1 = lc_xyz[(size_t)bg*3+1], l2 = lc_xyz[(size_t)bg*3+2];

    if (tid < KNB) {
        int idx = ki[(size_t)bg * KNB + tid];
        kidx[tid] = idx;
        const float* q = xyz + ((size_t)b * N + idx) * 3;
        float a0 = (q[0]-l0)*invz, a1 = (q[1]-l1)*invz, a2 = (q[2]-l2)*invz;
        float c0 = a1*l2 - a2*l1;          // cross(normed knn_xyz, raw lc_xyz)
        float c1 = a2*l0 - a0*l2;
        float c2 = a0*l1 - a1*l0;
        float dt = (a0*l0 + a1*l1) + a2*l2;
        float* tp = t7 + tid * 7;
        tp[0]=a0; tp[1]=a1; tp[2]=a2; tp[3]=c0; tp[4]=c1; tp[5]=c2; tp[6]=dt;
        sxyzn[tid*3]=a0; sxyzn[tid*3+1]=a1; sxyzn[tid*3+2]=a2;
    }
    __syncthreads();
    const float TWO_PI = 6.2831854820251465f;
    // fourier embedding: emb[k][c] = sin(proj)^5 / cos(proj)^5
    for (int i = tid; i < KNB * C2; i += blockDim.x) {
        int k = i / C2, m2 = i % C2;
        const float* tp = t7 + k * 7;
        float s = 0.0f;
        for (int j = 0; j < 7; ++j) s += tp[j] * Bmat[j * C2 + m2];
        float pr = TWO_PI * s;
        float sn = sinf(pr), cs = cosf(pr);
        float sn2 = sn*sn, cs2 = cs*cs;
        semb[k*C + m2]      = sn2*sn2*sn;
        semb[k*C + C2 + m2] = cs2*cs2*cs;
    }
    __syncthreads();
    // per output channel m: w = (knn_x_w + pe)*pe ; pooled = 2*mean_K(w)  (k_anp cancels)
    for (int m = tid; m < Cout; m += blockDim.x) {
        int c3 = m / (2 * F);
        int r  = m % (2 * F);
        int f  = r >> 1;
        int trig = r & 1;
        float de = powf(100.0f, (float)f / (float)F);
        float lv = (c3 == 0) ? l0 : ((c3 == 1) ? l1 : l2);
        float a2v = (1000.0f * lv) / de;
        float pe2 = trig ? cosf(a2v) : sinf(a2v);
        float lfm = (m < C) ? lc_x[(size_t)bg * C + m] : 0.0f;
        float acc = 0.0f;
        for (int k = 0; k < KNB; ++k) {
            float v;
            if (m < C) {
                v = (feats[((size_t)b * N + kidx[k]) * C + m] - lfm) * invx;
            } else {
                v = semb[k * C + (m - C)];
            }
            float a1v = (1000.0f * sxyzn[k*3 + c3]) / de;
            float pe1 = trig ? cosf(a1v) : sinf(a1v);
            float pe = pe1 + pe2;
            acc += (v + pe) * pe;
        }
        float mean = acc / 24.0f;
        pooled[((size_t)b * Cout + m) * G + g] = 2.0f * mean;   // k_anp + mean = 2*mean
    }
}

// ---------------------------------------------------------------- BatchNorm stats (train mode, biased var)
__global__ __launch_bounds__(256) void k_bnstats(const float* __restrict__ pooled,
                                                 float* __restrict__ stats,
                                                 int B, int Cout, int G) {
    int m = blockIdx.x;
    double s = 0.0, s2 = 0.0;
    for (int i = threadIdx.x; i < B * G; i += blockDim.x) {
        int b = i / G, g = i % G;
        float v = pooled[((size_t)b * Cout + m) * G + g];
        s += (double)v; s2 += (double)v * (double)v;
    }
    for (int off = 32; off > 0; off >>= 1) { s += __shfl_down(s, off); s2 += __shfl_down(s2, off); }
    __shared__ double sw[8], sw2[8];
    int wid = threadIdx.x >> 6;
    if ((threadIdx.x & 63) == 0) { sw[wid] = s; sw2[wid] = s2; }
    __syncthreads();
    if (threadIdx.x == 0) {
        int nw = blockDim.x >> 6;
        double ts = 0.0, ts2 = 0.0;
        for (int w = 0; w < nw; ++w) { ts += sw[w]; ts2 += sw2[w]; }
        double n = (double)(B * G);
        double mean = ts / n;
        double var = ts2 / n - mean * mean;
        stats[2*m]   = (float)mean;
        stats[2*m+1] = (float)var;
    }
}

// BN apply + exact GELU; transposed=1 writes [B,G,Cout] (feats layout for next stage)
__global__ void k_bn_gelu(const float* __restrict__ pooled, const float* __restrict__ stats,
                          const float* __restrict__ gamma, const float* __restrict__ beta,
                          float* __restrict__ out, int B, int Cout, int G, int transposed) {
    int i = blockIdx.x * blockDim.x + threadIdx.x;
    int tot = B * Cout * G;
    if (i >= tot) return;
    int g = i % G; int t = i / G; int m = t % Cout; int b = t / Cout;
    float v = pooled[i];
    float mean = stats[2*m], var = stats[2*m+1];
    float y = (v - mean) / sqrtf(var + 1e-5f) * gamma[m] + beta[m];
    float ge = 0.5f * y * (1.0f + erff(y / 1.4142135381698608f));
    if (transposed) out[((size_t)b * G + g) * Cout + m] = ge;
    else            out[i] = ge;
}

// ---------------------------------------------------------------- launch
extern "C" void kernel_launch(void* const* d_in, const int* in_sizes, int n_in,
                              void* d_out, int out_size, void* d_ws, size_t ws_size,
                              hipStream_t stream) {
    const int B = 4, N1 = 4096, C0 = 72, G1 = 2048, Co1 = 144;
    const int N2 = 2048, C1 = 144, G2 = 1024, Co2 = 288;

    const float* xyz = (const float*)d_in[0];
    const float* x0  = (const float*)d_in[1];
    const float* B0  = (const float*)d_in[2];
    const float* B1  = (const float*)d_in[3];
    const float* g0  = (const float*)d_in[4];
    const float* be0 = (const float*)d_in[5];
    const float* g1  = (const float*)d_in[6];
    const float* be1 = (const float*)d_in[7];
    float* out = (float*)d_out;

    char* wp = (char*)d_ws;
    size_t off = 0;
    auto A = [&](size_t bytes) -> void* {
        void* p = wp + off;
        off += (bytes + 255) & ~(size_t)255;
        return p;
    };
    float* feats1  = (float*)A((size_t)B*N1*C0*4);
    int*   fi1     = (int*)  A((size_t)B*G1*4);
    float* lcx1    = (float*)A((size_t)B*G1*3*4);
    float* lcf1    = (float*)A((size_t)B*G1*C0*4);
    int*   ki1     = (int*)  A((size_t)B*G1*KNB*4);
    double* acc    = (double*)A(8*8);
    float* inv1    = (float*)A(2*4);
    float* inv2    = (float*)A(2*4);
    float* pooled1 = (float*)A((size_t)B*Co1*G1*4);
    float* stats1  = (float*)A((size_t)Co1*2*4);
    float* feats2  = (float*)A((size_t)B*N2*C1*4);
    float* lcx2    = (float*)A((size_t)B*G2*3*4);
    float* stats2  = (float*)A((size_t)Co2*2*4);
    // aliases (lifetimes disjoint, sizes checked: equal or smaller)
    int*   fi2     = fi1;
    float* lcf2    = lcf1;     // B*G2*C1 == B*G1*C0
    int*   ki2     = ki1;
    float* pooled2 = feats1;   // B*Co2*G2 == B*N1*C0

    k_zero<<<1, 64, 0, stream>>>(acc);
    k_transpose<<<(B*C0*N1 + 255)/256, 256, 0, stream>>>(x0, feats1, B, C0, N1);

    // ---- stage 1 ----
    k_fps_t<8, 8><<<B, 512, (size_t)(2*8*8 + 3*N1)*4, stream>>>(xyz, fi1, N1, G1);
    k_gather<<<(B*G1*(C0+3) + 255)/256, 256, 0, stream>>>(xyz, feats1, fi1, lcx1, lcf1, B, N1, G1, C0);
    k_knn<<<B*G1, 256, (size_t)(N1 + 32)*4, stream>>>(xyz, lcx1, ki1, B, N1, G1);
    k_stdsum<<<512, 256, 0, stream>>>(feats1, lcf1, ki1, acc,     B, N1, G1, C0);
    k_stdsum<<<256, 256, 0, stream>>>(xyz,    lcx1, ki1, acc + 2, B, N1, G1, 3);
    k_finalize<<<1, 64, 0, stream>>>(acc, inv1, (double)B*G1*KNB*C0, (double)B*G1*KNB*3);
    {
        size_t shf = (size_t)(KNB*7 + KNB*3 + KNB + KNB*C0) * 4;
        k_feature<<<B*G1, 256, shf, stream>>>(xyz, feats1, lcx1, lcf1, ki1, B0, inv1, pooled1,
                                              B, N1, G1, C0);
    }
    k_bnstats<<<Co1, 256, 0, stream>>>(pooled1, stats1, B, Co1, G1);
    k_bn_gelu<<<(B*Co1*G1 + 255)/256, 256, 0, stream>>>(pooled1, stats1, g0, be0, feats2,
                                                        B, Co1, G1, 1);

    // ---- stage 2 (xyz = lcx1, feats = feats2) ----
    // FPS on an FPS-ordered prefix set is the identity permutation (prefix-nesting
    // theorem; exact incl. ties since selected points have dist 0 and any tied
    // maximizer has a later position). So fi2 = [0..G2).
    k_iota<<<(B*G2 + 255)/256, 256, 0, stream>>>(fi2, G2, B*G2);
    k_gather<<<(B*G2*(C1+3) + 255)/256, 256, 0, stream>>>(lcx1, feats2, fi2, lcx2, lcf2, B, N2, G2, C1);
    k_knn<<<B*G2, 256, (size_t)(N2 + 32)*4, stream>>>(lcx1, lcx2, ki2, B, N2, G2);
    k_stdsum<<<512, 256, 0, stream>>>(feats2, lcf2, ki2, acc + 4, B, N2, G2, C1);
    k_stdsum<<<256, 256, 0, stream>>>(lcx1,   lcx2, ki2, acc + 6, B, N2, G2, 3);
    k_finalize<<<1, 64, 0, stream>>>(acc + 4, inv2, (double)B*G2*KNB*C1, (double)B*G2*KNB*3);
    {
        size_t shf = (size_t)(KNB*7 + KNB*3 + KNB + KNB*C1) * 4;
        k_feature<<<B*G2, 256, shf, stream>>>(lcx1, feats2, lcx2, lcf2, ki2, B1, inv2, pooled2,
                                              B, N2, G2, C1);
    }
    k_bnstats<<<Co2, 256, 0, stream>>>(pooled2, stats2, B, Co2, G2);
    k_bn_gelu<<<(B*Co2*G2 + 255)/256, 256, 0, stream>>>(pooled2, stats2, g1, be1, out,
                                                        B, Co2, G2, 0);
}

// Round 4
// 2247.386 us; speedup vs baseline: 1.4103x; 1.4103x over previous
//
#include <hip/hip_runtime.h>
#include <math.h>

#define KNB 24

// ---------------------------------------------------------------- transpose + zero acc
// x [B,C,N] -> feats [B,N,C]; also zeroes the 8 fp64 accumulators (ws is re-poisoned each call)
__global__ void k_transpose(const float* __restrict__ x, float* __restrict__ feats,
                            double* __restrict__ acc, int B, int C, int N) {
    int idx = blockIdx.x * blockDim.x + threadIdx.x;
    if (idx < 8) acc[idx] = 0.0;
    int tot = B * C * N;
    if (idx >= tot) return;
    int n = idx % N; int t = idx / N; int c = t % C; int b = t / C;
    feats[((size_t)b * N + n) * C + c] = x[idx];
}

// ---------------------------------------------------------------- FPS
// DPP-based full-wave f32 max; result valid in lane 63.
// row_shr 1/2/4/8 then row_bcast15/31. bound_ctrl zero-fill safe (dists >= 0).
template<int CTRL>
__device__ __forceinline__ float dppmax(float v) {
    int t = __builtin_amdgcn_update_dpp(0, __float_as_int(v), CTRL, 0xf, 0xf, true);
    return fmaxf(v, __int_as_float(t));
}

// One workgroup per batch (4 waves, 256 thr). dist+xyz register-resident.
// One barrier/iter: per-wave packed u64 key -> parity-dbuf LDS slots -> all
// threads reduce 4 slots. Centroid refetched via single ds_read_b128.
template<int NPT, int NWAVE>
__global__ __launch_bounds__(64 * NWAVE) void k_fps_t(const float* __restrict__ xyz,
                                                      int* __restrict__ fi,
                                                      int N, int M) {
#pragma clang fp contract(off)
    const int b = blockIdx.x;
    const int tid = threadIdx.x;
    const int lane = tid & 63;
    const int wid = tid >> 6;
    extern __shared__ unsigned long long sm_u64[];
    unsigned long long* keys = sm_u64;                 // [2][NWAVE] parity dbuf
    float4* pts = (float4*)(sm_u64 + 2 * NWAVE);       // [N] packed xyz

    const float* p = xyz + (size_t)b * N * 3;
    for (int i = tid; i < N; i += 64 * NWAVE)
        pts[i] = make_float4(p[i*3], p[i*3+1], p[i*3+2], 0.0f);
    __syncthreads();

    const int base = tid * NPT;
    float rx[NPT], ry[NPT], rz[NPT], dist[NPT];
#pragma unroll
    for (int j = 0; j < NPT; ++j) {
        float4 q = pts[base + j];
        rx[j] = q.x; ry[j] = q.y; rz[j] = q.z;
        dist[j] = 1e10f;
    }

    int far = 0;
    float4 c0 = pts[0];
    float cx = c0.x, cy = c0.y, cz = c0.z;
    for (int it = 0; it < M; ++it) {
        if (tid == 0) fi[b * M + it] = far;            // record carry BEFORE update
        float bv = -1.0f; int bi = 0;
#pragma unroll
        for (int j = 0; j < NPT; ++j) {
            float dx = rx[j] - cx, dy = ry[j] - cy, dz = rz[j] - cz;
            float d = (dx*dx + dy*dy) + dz*dz;         // ((d0+d1)+d2), no fma
            float dd = fminf(dist[j], d);
            dist[j] = dd;
            if (dd > bv) { bv = dd; bi = base + j; }   // ascending j -> first-max kept
        }
        // DPP value-only wave max (fast path vs ds_bpermute butterfly)
        float r = bv;
        r = dppmax<0x111>(r); r = dppmax<0x112>(r);
        r = dppmax<0x114>(r); r = dppmax<0x118>(r);
        r = dppmax<0x142>(r); r = dppmax<0x143>(r);
        float wmax = __int_as_float(__builtin_amdgcn_readlane(__float_as_int(r), 63));
        // lowest lane holding the max = smallest global index
        unsigned long long mask = __ballot(bv == wmax);
        int src = __builtin_ctzll(mask);
        int wbi = __builtin_amdgcn_readlane(bi, src);
        // pack: max key -> max dist, tie -> min index
        unsigned long long key =
            ((unsigned long long)__float_as_uint(wmax) << 32) | (unsigned)(~wbi);
        if (lane == 0) keys[(it & 1) * NWAVE + wid] = key;
        __syncthreads();
        unsigned long long k0 = keys[(it & 1) * NWAVE + 0];
#pragma unroll
        for (int w = 1; w < NWAVE; ++w) {
            unsigned long long kw = keys[(it & 1) * NWAVE + w];
            if (kw > k0) k0 = kw;
        }
        far = (int)(~(unsigned)k0);
        float4 c = pts[far];                           // single ds_read_b128
        cx = c.x; cy = c.y; cz = c.z;
    }
}

// ---------------------------------------------------------------- kNN + center gather fused
// 24 smallest, ties->lower idx. Also writes lc_xyz / lc_x for this bg.
__global__ __launch_bounds__(256) void k_knn(const float* __restrict__ xyz,
                                             const float* __restrict__ feats,
                                             const int* __restrict__ fi,
                                             float* __restrict__ lc_xyz,
                                             float* __restrict__ lc_x,
                                             int* __restrict__ ki,
                                             int B, int N, int G, int C, int identity) {
#pragma clang fp contract(off)
    int bg = blockIdx.x; int b = bg / G; int g = bg % G;
    int idx = identity ? g : fi[bg];
    extern __shared__ float sd[];
    float* rv = sd + N; int* ri = (int*)(rv + 8);
    const float* p = xyz + (size_t)b * N * 3;
    float cx = p[idx*3], cy = p[idx*3+1], cz = p[idx*3+2];
    if (threadIdx.x < 3) lc_xyz[(size_t)bg * 3 + threadIdx.x] = p[idx*3 + threadIdx.x];
    for (int c = threadIdx.x; c < C; c += blockDim.x)
        lc_x[(size_t)bg * C + c] = feats[((size_t)b * N + idx) * C + c];
    float cc = (cx*cx + cy*cy) + cz*cz;
    for (int i = threadIdx.x; i < N; i += blockDim.x) {
        float x0 = p[i*3], x1 = p[i*3+1], x2 = p[i*3+2];
        float xx = (x0*x0 + x1*x1) + x2*x2;
        float dt = (cx*x0 + cy*x1) + cz*x2;
        sd[i] = (cc - 2.0f*dt) + xx;          // (cc - 2dot) + xx, matches ref assoc
    }
    __syncthreads();
    for (int kk = 0; kk < KNB; ++kk) {
        float bv = 1e30f; int bi = N;
        for (int i = threadIdx.x; i < N; i += blockDim.x) {
            float v = sd[i];
            if (v < bv) { bv = v; bi = i; }   // i increasing -> first-min kept
        }
        for (int off = 32; off > 0; off >>= 1) {
            float ov = __shfl_down(bv, off); int oi = __shfl_down(bi, off);
            if (ov < bv || (ov == bv && oi < bi)) { bv = ov; bi = oi; }
        }
        int wid = threadIdx.x >> 6;
        if ((threadIdx.x & 63) == 0) { rv[wid] = bv; ri[wid] = bi; }
        __syncthreads();
        if (threadIdx.x == 0) {
            int nw = blockDim.x >> 6;
            float v = rv[0]; int ii = ri[0];
            for (int w = 1; w < nw; ++w) {
                if (rv[w] < v || (rv[w] == v && ri[w] < ii)) { v = rv[w]; ii = ri[w]; }
            }
            ki[(size_t)bg * KNB + kk] = ii;
            sd[ii] = 1e30f;
        }
        __syncthreads();
    }
}

// ---------------------------------------------------------------- fused global std reductions
// loop1: feature diffs -> acc[0..1]; loop2: xyz diffs -> acc[2..3]
__global__ void k_stdsum(const float* __restrict__ feats, const float* __restrict__ xyzp,
                         const float* __restrict__ lc_x, const float* __restrict__ lc_xyz,
                         const int* __restrict__ ki, double* __restrict__ acc,
                         int B, int N, int G, int C) {
    size_t tot1 = (size_t)B * G * KNB * C;
    size_t tot2 = (size_t)B * G * KNB * 3;
    double s = 0.0, s2 = 0.0, s3 = 0.0, s4 = 0.0;
    size_t stride = (size_t)gridDim.x * blockDim.x;
    size_t i0 = (size_t)blockIdx.x * blockDim.x + threadIdx.x;
    for (size_t i = i0; i < tot1; i += stride) {
        int c = (int)(i % C); size_t t = i / C; int k = (int)(t % KNB); size_t bg = t / KNB;
        int b = (int)(bg / G);
        int idx = ki[bg * KNB + k];
        float d = feats[((size_t)b * N + idx) * C + c] - lc_x[bg * C + c];
        s += (double)d; s2 += (double)d * (double)d;
    }
    for (size_t i = i0; i < tot2; i += stride) {
        int c = (int)(i % 3); size_t t = i / 3; int k = (int)(t % KNB); size_t bg = t / KNB;
        int b = (int)(bg / G);
        int idx = ki[bg * KNB + k];
        float d = xyzp[((size_t)b * N + idx) * 3 + c] - lc_xyz[bg * 3 + c];
        s3 += (double)d; s4 += (double)d * (double)d;
    }
    for (int off = 32; off > 0; off >>= 1) {
        s += __shfl_down(s, off); s2 += __shfl_down(s2, off);
        s3 += __shfl_down(s3, off); s4 += __shfl_down(s4, off);
    }
    if ((threadIdx.x & 63) == 0) {
        atomicAdd(acc, s); atomicAdd(acc + 1, s2);
        atomicAdd(acc + 2, s3); atomicAdd(acc + 3, s4);
    }
}

// ---------------------------------------------------------------- LGA feature + pool (one wg per (b,g))
// finalize (std -> 1/(std+eps)) inlined redundantly per block.
__global__ __launch_bounds__(256) void k_feature(
    const float* __restrict__ xyz, const float* __restrict__ feats,
    const float* __restrict__ lc_xyz, const float* __restrict__ lc_x,
    const int* __restrict__ ki, const float* __restrict__ Bmat,
    const double* __restrict__ accp, float* __restrict__ pooled,
    int B, int N, int G, int C, double nx, double nz)
{
    int bg = blockIdx.x; int b = bg / G; int g = bg % G;
    int tid = threadIdx.x;
    int C2 = C >> 1;
    int Cout = 2 * C;
    int F = C / 3;                         // tr_embed F = (2C)/(2*3)
    extern __shared__ float sm[];
    float* t7    = sm;                     // [24][7]
    float* sxyzn = t7 + KNB * 7;           // [24][3]
    int*   kidx  = (int*)(sxyzn + KNB * 3);// [24]
    float* semb  = (float*)(kidx + KNB);   // [24][C]

    // inline finalize (identical arithmetic to the old k_finalize)
    double a0 = accp[0], a1 = accp[1], a2 = accp[2], a3 = accp[3];
    double vx = (a1 - a0 * a0 / nx) / (nx - 1.0);
    float invx = 1.0f / (sqrtf((float)vx) + 1e-5f);
    double vz = (a3 - a2 * a2 / nz) / (nz - 1.0);
    float invz = 1.0f / (sqrtf((float)vz) + 1e-5f);

    float l0 = lc_xyz[(size_t)bg*3], l1 = lc_xyz[(size_t)bg*3+1], l2 = lc_xyz[(size_t)bg*3+2];

    if (tid < KNB) {
        int idx = ki[(size_t)bg * KNB + tid];
        kidx[tid] = idx;
        const float* q = xyz + ((size_t)b * N + idx) * 3;
        float a0f = (q[0]-l0)*invz, a1f = (q[1]-l1)*invz, a2f = (q[2]-l2)*invz;
        float c0 = a1f*l2 - a2f*l1;        // cross(normed knn_xyz, raw lc_xyz)
        float c1 = a2f*l0 - a0f*l2;
        float c2 = a0f*l1 - a1f*l0;
        float dt = (a0f*l0 + a1f*l1) + a2f*l2;
        float* tp = t7 + tid * 7;
        tp[0]=a0f; tp[1]=a1f; tp[2]=a2f; tp[3]=c0; tp[4]=c1; tp[5]=c2; tp[6]=dt;
        sxyzn[tid*3]=a0f; sxyzn[tid*3+1]=a1f; sxyzn[tid*3+2]=a2f;
    }
    __syncthreads();
    const float TWO_PI = 6.2831854820251465f;
    // fourier embedding: emb[k][c] = sin(proj)^5 / cos(proj)^5
    for (int i = tid; i < KNB * C2; i += blockDim.x) {
        int k = i / C2, m2 = i % C2;
        const float* tp = t7 + k * 7;
        float s = 0.0f;
        for (int j = 0; j < 7; ++j) s += tp[j] * Bmat[j * C2 + m2];
        float pr = TWO_PI * s;
        float sn = sinf(pr), cs = cosf(pr);
        float sn2 = sn*sn, cs2 = cs*cs;
        semb[k*C + m2]      = sn2*sn2*sn;
        semb[k*C + C2 + m2] = cs2*cs2*cs;
    }
    __syncthreads();
    // per output channel m: w = (knn_x_w + pe)*pe ; pooled = 2*mean_K(w)  (k_anp cancels)
    for (int m = tid; m < Cout; m += blockDim.x) {
        int c3 = m / (2 * F);
        int r  = m % (2 * F);
        int f  = r >> 1;
        int trig = r & 1;
        float de = powf(100.0f, (float)f / (float)F);
        float lv = (c3 == 0) ? l0 : ((c3 == 1) ? l1 : l2);
        float a2v = (1000.0f * lv) / de;
        float pe2 = trig ? cosf(a2v) : sinf(a2v);
        float lfm = (m < C) ? lc_x[(size_t)bg * C + m] : 0.0f;
        float acc = 0.0f;
        for (int k = 0; k < KNB; ++k) {
            float v;
            if (m < C) {
                v = (feats[((size_t)b * N + kidx[k]) * C + m] - lfm) * invx;
            } else {
                v = semb[k * C + (m - C)];
            }
            float a1v = (1000.0f * sxyzn[k*3 + c3]) / de;
            float pe1 = trig ? cosf(a1v) : sinf(a1v);
            float pe = pe1 + pe2;
            acc += (v + pe) * pe;
        }
        float mean = acc / 24.0f;
        pooled[((size_t)b * Cout + m) * G + g] = 2.0f * mean;   // k_anp + mean = 2*mean
    }
}

// ---------------------------------------------------------------- fused BatchNorm(train) + exact GELU
// one block per channel: pass1 stats (biased var, fp64), pass2 apply+write.
// transposed=1 writes [B,G,Cout] (feats layout for next stage)
__global__ __launch_bounds__(256) void k_bn(const float* __restrict__ pooled,
                                            const float* __restrict__ gamma,
                                            const float* __restrict__ beta,
                                            float* __restrict__ out,
                                            int B, int Cout, int G, int transposed) {
    int m = blockIdx.x;
    double s = 0.0, s2 = 0.0;
    for (int i = threadIdx.x; i < B * G; i += 256) {
        int b = i / G, g = i % G;
        float v = pooled[((size_t)b * Cout + m) * G + g];
        s += (double)v; s2 += (double)v * (double)v;
    }
    for (int off = 32; off > 0; off >>= 1) { s += __shfl_down(s, off); s2 += __shfl_down(s2, off); }
    __shared__ double sw[4], sw2[4];
    __shared__ float smv[2];
    int wid = threadIdx.x >> 6;
    if ((threadIdx.x & 63) == 0) { sw[wid] = s; sw2[wid] = s2; }
    __syncthreads();
    if (threadIdx.x == 0) {
        double ts = sw[0] + sw[1] + sw[2] + sw[3];
        double ts2 = sw2[0] + sw2[1] + sw2[2] + sw2[3];
        double n = (double)(B * G);
        double mean = ts / n;
        double var = ts2 / n - mean * mean;
        smv[0] = (float)mean; smv[1] = (float)var;
    }
    __syncthreads();
    float mean = smv[0], var = smv[1];
    float ga = gamma[m], be = beta[m];
    for (int i = threadIdx.x; i < B * G; i += 256) {
        int b = i / G, g = i % G;
        float v = pooled[((size_t)b * Cout + m) * G + g];
        float y = (v - mean) / sqrtf(var + 1e-5f) * ga + be;
        float ge = 0.5f * y * (1.0f + erff(y / 1.4142135381698608f));
        if (transposed) out[((size_t)b * G + g) * Cout + m] = ge;
        else            out[((size_t)b * Cout + m) * G + g] = ge;
    }
}

// ---------------------------------------------------------------- launch
extern "C" void kernel_launch(void* const* d_in, const int* in_sizes, int n_in,
                              void* d_out, int out_size, void* d_ws, size_t ws_size,
                              hipStream_t stream) {
    const int B = 4, N1 = 4096, C0 = 72, G1 = 2048, Co1 = 144;
    const int N2 = 2048, C1 = 144, G2 = 1024, Co2 = 288;

    const float* xyz = (const float*)d_in[0];
    const float* x0  = (const float*)d_in[1];
    const float* B0  = (const float*)d_in[2];
    const float* B1  = (const float*)d_in[3];
    const float* g0  = (const float*)d_in[4];
    const float* be0 = (const float*)d_in[5];
    const float* g1  = (const float*)d_in[6];
    const float* be1 = (const float*)d_in[7];
    float* out = (float*)d_out;

    char* wp = (char*)d_ws;
    size_t off = 0;
    auto A = [&](size_t bytes) -> void* {
        void* p = wp + off;
        off += (bytes + 255) & ~(size_t)255;
        return p;
    };
    float* feats1  = (float*)A((size_t)B*N1*C0*4);
    int*   fi1     = (int*)  A((size_t)B*G1*4);
    float* lcx1    = (float*)A((size_t)B*G1*3*4);
    float* lcf1    = (float*)A((size_t)B*G1*C0*4);
    int*   ki1     = (int*)  A((size_t)B*G1*KNB*4);
    double* acc    = (double*)A(8*8);
    float* pooled1 = (float*)A((size_t)B*Co1*G1*4);
    float* feats2  = (float*)A((size_t)B*N2*C1*4);
    float* lcx2    = (float*)A((size_t)B*G2*3*4);
    // aliases (lifetimes disjoint, sizes equal)
    float* lcf2    = lcf1;     // B*G2*C1 == B*G1*C0
    int*   ki2     = ki1;
    float* pooled2 = feats1;   // B*Co2*G2 == B*N1*C0

    // 1. transpose + zero acc
    k_transpose<<<(B*C0*N1 + 255)/256, 256, 0, stream>>>(x0, feats1, acc, B, C0, N1);

    // ---- stage 1 ----
    // 2. FPS (4 waves, NPT=16, DPP butterfly, float4 LDS)
    k_fps_t<16, 4><<<B, 256, (size_t)(2*4*8 + N1*16), stream>>>(xyz, fi1, N1, G1);
    // 3. kNN + center gather
    k_knn<<<B*G1, 256, (size_t)(N1 + 32)*4, stream>>>(xyz, feats1, fi1, lcx1, lcf1, ki1,
                                                      B, N1, G1, C0, 0);
    // 4. fused std sums -> acc[0..3]
    k_stdsum<<<512, 256, 0, stream>>>(feats1, xyz, lcf1, lcx1, ki1, acc, B, N1, G1, C0);
    // 5. feature + pool (finalize inlined)
    {
        size_t shf = (size_t)(KNB*7 + KNB*3 + KNB + KNB*C0) * 4;
        k_feature<<<B*G1, 256, shf, stream>>>(xyz, feats1, lcx1, lcf1, ki1, B0, acc, pooled1,
                                              B, N1, G1, C0,
                                              (double)B*G1*KNB*C0, (double)B*G1*KNB*3);
    }
    // 6. BN + GELU (transposed -> feats layout for stage 2)
    k_bn<<<Co1, 256, 0, stream>>>(pooled1, g0, be0, feats2, B, Co1, G1, 1);

    // ---- stage 2 (xyz = lcx1, feats = feats2) ----
    // FPS on an FPS-ordered prefix set is the identity permutation (prefix-nesting;
    // exact incl. ties since selected points have dist 0 and any tied maximizer has
    // a later position). So centers are simply the first G2 points -> identity=1.
    // 7. kNN + identity center gather
    k_knn<<<B*G2, 256, (size_t)(N2 + 32)*4, stream>>>(lcx1, feats2, (const int*)nullptr,
                                                      lcx2, lcf2, ki2, B, N2, G2, C1, 1);
    // 8. fused std sums -> acc[4..7]
    k_stdsum<<<512, 256, 0, stream>>>(feats2, lcx1, lcf2, lcx2, ki2, acc + 4, B, N2, G2, C1);
    // 9. feature + pool
    {
        size_t shf = (size_t)(KNB*7 + KNB*3 + KNB + KNB*C1) * 4;
        k_feature<<<B*G2, 256, shf, stream>>>(lcx1, feats2, lcx2, lcf2, ki2, B1, acc + 4, pooled2,
                                              B, N2, G2, C1,
                                              (double)B*G2*KNB*C1, (double)B*G2*KNB*3);
    }
    // 10. BN + GELU -> final output
    k_bn<<<Co2, 256, 0, stream>>>(pooled2, g1, be1, out, B, Co2, G2, 0);
}

// Round 5
// 2210.547 us; speedup vs baseline: 1.4338x; 1.0167x over previous
//
#include <hip/hip_runtime.h>
#include <math.h>

#define KNB 24

typedef float v2f __attribute__((ext_vector_type(2)));

// ---------------------------------------------------------------- transpose + zero acc
// x [B,C,N] -> feats [B,N,C]; also zeroes the 8 fp64 accumulators (ws is re-poisoned each call)
__global__ void k_transpose(const float* __restrict__ x, float* __restrict__ feats,
                            double* __restrict__ acc, int B, int C, int N) {
    int idx = blockIdx.x * blockDim.x + threadIdx.x;
    if (idx < 8) acc[idx] = 0.0;
    int tot = B * C * N;
    if (idx >= tot) return;
    int n = idx % N; int t = idx / N; int c = t % C; int b = t / C;
    feats[((size_t)b * N + n) * C + c] = x[idx];
}

// ---------------------------------------------------------------- FPS
// DPP-based full-wave f32 max; result valid in lane 63.
template<int CTRL>
__device__ __forceinline__ float dppmax(float v) {
    int t = __builtin_amdgcn_update_dpp(0, __float_as_int(v), CTRL, 0xf, 0xf, true);
    return fmaxf(v, __int_as_float(t));
}

// One workgroup per batch (4 waves). dist+xyz in packed-f32 registers (v_pk_*).
// Loop contains ZERO global-memory ops (fi buffered in LDS, written at end) so
// the pre-barrier s_waitcnt vmcnt(0) is free. One barrier/iter; per-wave u64
// key exchange in parity-dbuf LDS; centroid refetch = one ds_read_b128.
template<int NPT, int NWAVE>   // NPT even
__global__ __launch_bounds__(64 * NWAVE) void k_fps_t(const float* __restrict__ xyz,
                                                      int* __restrict__ fi,
                                                      int N, int M) {
#pragma clang fp contract(off)
    const int NP2 = NPT / 2;
    const int b = blockIdx.x;
    const int tid = threadIdx.x;
    const int lane = tid & 63;
    const int wid = tid >> 6;
    extern __shared__ unsigned long long sm_u64[];
    unsigned long long* keys = sm_u64;                    // [2][NWAVE] parity dbuf
    int* fi_lds = (int*)(sm_u64 + 2 * NWAVE);             // [M]
    float4* pts = (float4*)(fi_lds + M);                  // [N] packed xyz

    const float* p = xyz + (size_t)b * N * 3;
    for (int i = tid; i < N; i += 64 * NWAVE)
        pts[i] = make_float4(p[i*3], p[i*3+1], p[i*3+2], 0.0f);
    __syncthreads();

    const int base = tid * NPT;
    v2f rx[NP2], ry[NP2], rz[NP2], dist[NP2];
#pragma unroll
    for (int j = 0; j < NP2; ++j) {
        float4 a = pts[base + 2*j];
        float4 c = pts[base + 2*j + 1];
        rx[j] = (v2f){a.x, c.x}; ry[j] = (v2f){a.y, c.y}; rz[j] = (v2f){a.z, c.z};
        dist[j] = (v2f){1e10f, 1e10f};
    }

    int far = 0;
    float4 cpt = pts[0];
    float cx = cpt.x, cy = cpt.y, cz = cpt.z;
    for (int it = 0; it < M; ++it) {
        if (tid == 0) fi_lds[it] = far;               // record carry BEFORE update
        v2f cx2 = (v2f){cx, cx}, cy2 = (v2f){cy, cy}, cz2 = (v2f){cz, cz};
        v2f bv2 = (v2f){-1.0f, -1.0f};
#pragma unroll
        for (int j = 0; j < NP2; ++j) {
            v2f dx = rx[j] - cx2, dy = ry[j] - cy2, dz = rz[j] - cz2;
            v2f d = (dx*dx + dy*dy) + dz*dz;          // ((d0+d1)+d2) per elem, no fma
            v2f dd = __builtin_elementwise_min(dist[j], d);
            dist[j] = dd;
            bv2 = __builtin_elementwise_max(bv2, dd);
        }
        float bv = fmaxf(bv2.x, bv2.y);
        // first-match (smallest local index): descending overwrite, .y before .x
        int bi = 0;
#pragma unroll
        for (int j = NP2 - 1; j >= 0; --j) {
            if (dist[j].y == bv) bi = base + 2*j + 1;
            if (dist[j].x == bv) bi = base + 2*j;
        }
        // DPP value-only wave max (independent of the rescan above -> ILP)
        float r = bv;
        r = dppmax<0x111>(r); r = dppmax<0x112>(r);
        r = dppmax<0x114>(r); r = dppmax<0x118>(r);
        r = dppmax<0x142>(r); r = dppmax<0x143>(r);
        float wmax = __int_as_float(__builtin_amdgcn_readlane(__float_as_int(r), 63));
        // lowest lane holding the max = smallest global index
        unsigned long long mask = __ballot(bv == wmax);
        int src = __builtin_ctzll(mask);
        int wbi = __builtin_amdgcn_readlane(bi, src);
        // pack: max key -> max dist, tie -> min index
        unsigned long long key =
            ((unsigned long long)__float_as_uint(wmax) << 32) | (unsigned)(~wbi);
        if (lane == 0) keys[(it & 1) * NWAVE + wid] = key;
        __syncthreads();
        unsigned long long k0 = keys[(it & 1) * NWAVE + 0];
#pragma unroll
        for (int w = 1; w < NWAVE; ++w) {
            unsigned long long kw = keys[(it & 1) * NWAVE + w];
            if (kw > k0) k0 = kw;
        }
        far = (int)(~(unsigned)k0);
        float4 c = pts[far];                           // single ds_read_b128
        cx = c.x; cy = c.y; cz = c.z;
    }
    __syncthreads();
    for (int i = tid; i < M; i += 64 * NWAVE) fi[b * M + i] = fi_lds[i];
}

// ---------------------------------------------------------------- kNN + center gather fused
// 24 smallest, ties->lower idx. Also writes lc_xyz / lc_x for this bg.
__global__ __launch_bounds__(256) void k_knn(const float* __restrict__ xyz,
                                             const float* __restrict__ feats,
                                             const int* __restrict__ fi,
                                             float* __restrict__ lc_xyz,
                                             float* __restrict__ lc_x,
                                             int* __restrict__ ki,
                                             int B, int N, int G, int C, int identity) {
#pragma clang fp contract(off)
    int bg = blockIdx.x; int b = bg / G; int g = bg % G;
    int idx = identity ? g : fi[bg];
    extern __shared__ float sd[];
    float* rv = sd + N; int* ri = (int*)(rv + 8);
    const float* p = xyz + (size_t)b * N * 3;
    float cx = p[idx*3], cy = p[idx*3+1], cz = p[idx*3+2];
    if (threadIdx.x < 3) lc_xyz[(size_t)bg * 3 + threadIdx.x] = p[idx*3 + threadIdx.x];
    for (int c = threadIdx.x; c < C; c += blockDim.x)
        lc_x[(size_t)bg * C + c] = feats[((size_t)b * N + idx) * C + c];
    float cc = (cx*cx + cy*cy) + cz*cz;
    for (int i = threadIdx.x; i < N; i += blockDim.x) {
        float x0 = p[i*3], x1 = p[i*3+1], x2 = p[i*3+2];
        float xx = (x0*x0 + x1*x1) + x2*x2;
        float dt = (cx*x0 + cy*x1) + cz*x2;
        sd[i] = (cc - 2.0f*dt) + xx;          // (cc - 2dot) + xx, matches ref assoc
    }
    __syncthreads();
    for (int kk = 0; kk < KNB; ++kk) {
        float bv = 1e30f; int bi = N;
        for (int i = threadIdx.x; i < N; i += blockDim.x) {
            float v = sd[i];
            if (v < bv) { bv = v; bi = i; }   // i increasing -> first-min kept
        }
        for (int off = 32; off > 0; off >>= 1) {
            float ov = __shfl_down(bv, off); int oi = __shfl_down(bi, off);
            if (ov < bv || (ov == bv && oi < bi)) { bv = ov; bi = oi; }
        }
        int wid = threadIdx.x >> 6;
        if ((threadIdx.x & 63) == 0) { rv[wid] = bv; ri[wid] = bi; }
        __syncthreads();
        if (threadIdx.x == 0) {
            int nw = blockDim.x >> 6;
            float v = rv[0]; int ii = ri[0];
            for (int w = 1; w < nw; ++w) {
                if (rv[w] < v || (rv[w] == v && ri[w] < ii)) { v = rv[w]; ii = ri[w]; }
            }
            ki[(size_t)bg * KNB + kk] = ii;
            sd[ii] = 1e30f;
        }
        __syncthreads();
    }
}

// ---------------------------------------------------------------- fused global std reductions
// loop1: feature diffs -> acc[0..1]; loop2: xyz diffs -> acc[2..3]
__global__ void k_stdsum(const float* __restrict__ feats, const float* __restrict__ xyzp,
                         const float* __restrict__ lc_x, const float* __restrict__ lc_xyz,
                         const int* __restrict__ ki, double* __restrict__ acc,
                         int B, int N, int G, int C) {
    size_t tot1 = (size_t)B * G * KNB * C;
    size_t tot2 = (size_t)B * G * KNB * 3;
    double s = 0.0, s2 = 0.0, s3 = 0.0, s4 = 0.0;
    size_t stride = (size_t)gridDim.x * blockDim.x;
    size_t i0 = (size_t)blockIdx.x * blockDim.x + threadIdx.x;
    for (size_t i = i0; i < tot1; i += stride) {
        int c = (int)(i % C); size_t t = i / C; int k = (int)(t % KNB); size_t bg = t / KNB;
        int b = (int)(bg / G);
        int idx = ki[bg * KNB + k];
        float d = feats[((size_t)b * N + idx) * C + c] - lc_x[bg * C + c];
        s += (double)d; s2 += (double)d * (double)d;
    }
    for (size_t i = i0; i < tot2; i += stride) {
        int c = (int)(i % 3); size_t t = i / 3; int k = (int)(t % KNB); size_t bg = t / KNB;
        int b = (int)(bg / G);
        int idx = ki[bg * KNB + k];
        float d = xyzp[((size_t)b * N + idx) * 3 + c] - lc_xyz[bg * 3 + c];
        s3 += (double)d; s4 += (double)d * (double)d;
    }
    for (int off = 32; off > 0; off >>= 1) {
        s += __shfl_down(s, off); s2 += __shfl_down(s2, off);
        s3 += __shfl_down(s3, off); s4 += __shfl_down(s4, off);
    }
    if ((threadIdx.x & 63) == 0) {
        atomicAdd(acc, s); atomicAdd(acc + 1, s2);
        atomicAdd(acc + 2, s3); atomicAdd(acc + 3, s4);
    }
}

// ---------------------------------------------------------------- LGA feature + pool (one wg per (b,g))
// finalize (std -> 1/(std+eps)) inlined redundantly per block.
__global__ __launch_bounds__(256) void k_feature(
    const float* __restrict__ xyz, const float* __restrict__ feats,
    const float* __restrict__ lc_xyz, const float* __restrict__ lc_x,
    const int* __restrict__ ki, const float* __restrict__ Bmat,
    const double* __restrict__ accp, float* __restrict__ pooled,
    int B, int N, int G, int C, double nx, double nz)
{
    int bg = blockIdx.x; int b = bg / G; int g = bg % G;
    int tid = threadIdx.x;
    int C2 = C >> 1;
    int Cout = 2 * C;
    int F = C / 3;                         // tr_embed F = (2C)/(2*3)
    extern __shared__ float sm[];
    float* t7    = sm;                     // [24][7]
    float* sxyzn = t7 + KNB * 7;           // [24][3]
    int*   kidx  = (int*)(sxyzn + KNB * 3);// [24]
    float* semb  = (float*)(kidx + KNB);   // [24][C]

    // inline finalize (identical arithmetic to the old k_finalize)
    double a0 = accp[0], a1 = accp[1], a2 = accp[2], a3 = accp[3];
    double vx = (a1 - a0 * a0 / nx) / (nx - 1.0);
    float invx = 1.0f / (sqrtf((float)vx) + 1e-5f);
    double vz = (a3 - a2 * a2 / nz) / (nz - 1.0);
    float invz = 1.0f / (sqrtf((float)vz) + 1e-5f);

    float l0 = lc_xyz[(size_t)bg*3], l1 = lc_xyz[(size_t)bg*3+1], l2 = lc_xyz[(size_t)bg*3+2];

    if (tid < KNB) {
        int idx = ki[(size_t)bg * KNB + tid];
        kidx[tid] = idx;
        const float* q = xyz + ((size_t)b * N + idx) * 3;
        float a0f = (q[0]-l0)*invz, a1f = (q[1]-l1)*invz, a2f = (q[2]-l2)*invz;
        float c0 = a1f*l2 - a2f*l1;        // cross(normed knn_xyz, raw lc_xyz)
        float c1 = a2f*l0 - a0f*l2;
        float c2 = a0f*l1 - a1f*l0;
        float dt = (a0f*l0 + a1f*l1) + a2f*l2;
        float* tp = t7 + tid * 7;
        tp[0]=a0f; tp[1]=a1f; tp[2]=a2f; tp[3]=c0; tp[4]=c1; tp[5]=c2; tp[6]=dt;
        sxyzn[tid*3]=a0f; sxyzn[tid*3+1]=a1f; sxyzn[tid*3+2]=a2f;
    }
    __syncthreads();
    const float TWO_PI = 6.2831854820251465f;
    // fourier embedding: emb[k][c] = sin(proj)^5 / cos(proj)^5
    for (int i = tid; i < KNB * C2; i += blockDim.x) {
        int k = i / C2, m2 = i % C2;
        const float* tp = t7 + k * 7;
        float s = 0.0f;
        for (int j = 0; j < 7; ++j) s += tp[j] * Bmat[j * C2 + m2];
        float pr = TWO_PI * s;
        float sn = sinf(pr), cs = cosf(pr);
        float sn2 = sn*sn, cs2 = cs*cs;
        semb[k*C + m2]      = sn2*sn2*sn;
        semb[k*C + C2 + m2] = cs2*cs2*cs;
    }
    __syncthreads();
    // per output channel m: w = (knn_x_w + pe)*pe ; pooled = 2*mean_K(w)  (k_anp cancels)
    for (int m = tid; m < Cout; m += blockDim.x) {
        int c3 = m / (2 * F);
        int r  = m % (2 * F);
        int f  = r >> 1;
        int trig = r & 1;
        float de = powf(100.0f, (float)f / (float)F);
        float lv = (c3 == 0) ? l0 : ((c3 == 1) ? l1 : l2);
        float a2v = (1000.0f * lv) / de;
        float pe2 = trig ? cosf(a2v) : sinf(a2v);
        float lfm = (m < C) ? lc_x[(size_t)bg * C + m] : 0.0f;
        float acc = 0.0f;
        for (int k = 0; k < KNB; ++k) {
            float v;
            if (m < C) {
                v = (feats[((size_t)b * N + kidx[k]) * C + m] - lfm) * invx;
            } else {
                v = semb[k * C + (m - C)];
            }
            float a1v = (1000.0f * sxyzn[k*3 + c3]) / de;
            float pe1 = trig ? cosf(a1v) : sinf(a1v);
            float pe = pe1 + pe2;
            acc += (v + pe) * pe;
        }
        float mean = acc / 24.0f;
        pooled[((size_t)b * Cout + m) * G + g] = 2.0f * mean;   // k_anp + mean = 2*mean
    }
}

// ---------------------------------------------------------------- fused BatchNorm(train) + exact GELU
// one block per channel: pass1 stats (biased var, fp64), pass2 apply+write.
// transposed=1 writes [B,G,Cout] (feats layout for next stage)
__global__ __launch_bounds__(256) void k_bn(const float* __restrict__ pooled,
                                            const float* __restrict__ gamma,
                                            const float* __restrict__ beta,
                                            float* __restrict__ out,
                                            int B, int Cout, int G, int transposed) {
    int m = blockIdx.x;
    double s = 0.0, s2 = 0.0;
    for (int i = threadIdx.x; i < B * G; i += 256) {
        int b = i / G, g = i % G;
        float v = pooled[((size_t)b * Cout + m) * G + g];
        s += (double)v; s2 += (double)v * (double)v;
    }
    for (int off = 32; off > 0; off >>= 1) { s += __shfl_down(s, off); s2 += __shfl_down(s2, off); }
    __shared__ double sw[4], sw2[4];
    __shared__ float smv[2];
    int wid = threadIdx.x >> 6;
    if ((threadIdx.x & 63) == 0) { sw[wid] = s; sw2[wid] = s2; }
    __syncthreads();
    if (threadIdx.x == 0) {
        double ts = sw[0] + sw[1] + sw[2] + sw[3];
        double ts2 = sw2[0] + sw2[1] + sw2[2] + sw2[3];
        double n = (double)(B * G);
        double mean = ts / n;
        double var = ts2 / n - mean * mean;
        smv[0] = (float)mean; smv[1] = (float)var;
    }
    __syncthreads();
    float mean = smv[0], var = smv[1];
    float ga = gamma[m], be = beta[m];
    for (int i = threadIdx.x; i < B * G; i += 256) {
        int b = i / G, g = i % G;
        float v = pooled[((size_t)b * Cout + m) * G + g];
        float y = (v - mean) / sqrtf(var + 1e-5f) * ga + be;
        float ge = 0.5f * y * (1.0f + erff(y / 1.4142135381698608f));
        if (transposed) out[((size_t)b * G + g) * Cout + m] = ge;
        else            out[((size_t)b * Cout + m) * G + g] = ge;
    }
}

// ---------------------------------------------------------------- launch
extern "C" void kernel_launch(void* const* d_in, const int* in_sizes, int n_in,
                              void* d_out, int out_size, void* d_ws, size_t ws_size,
                              hipStream_t stream) {
    const int B = 4, N1 = 4096, C0 = 72, G1 = 2048, Co1 = 144;
    const int N2 = 2048, C1 = 144, G2 = 1024, Co2 = 288;

    const float* xyz = (const float*)d_in[0];
    const float* x0  = (const float*)d_in[1];
    const float* B0  = (const float*)d_in[2];
    const float* B1  = (const float*)d_in[3];
    const float* g0  = (const float*)d_in[4];
    const float* be0 = (const float*)d_in[5];
    const float* g1  = (const float*)d_in[6];
    const float* be1 = (const float*)d_in[7];
    float* out = (float*)d_out;

    char* wp = (char*)d_ws;
    size_t off = 0;
    auto A = [&](size_t bytes) -> void* {
        void* p = wp + off;
        off += (bytes + 255) & ~(size_t)255;
        return p;
    };
    float* feats1  = (float*)A((size_t)B*N1*C0*4);
    int*   fi1     = (int*)  A((size_t)B*G1*4);
    float* lcx1    = (float*)A((size_t)B*G1*3*4);
    float* lcf1    = (float*)A((size_t)B*G1*C0*4);
    int*   ki1     = (int*)  A((size_t)B*G1*KNB*4);
    double* acc    = (double*)A(8*8);
    float* pooled1 = (float*)A((size_t)B*Co1*G1*4);
    float* feats2  = (float*)A((size_t)B*N2*C1*4);
    float* lcx2    = (float*)A((size_t)B*G2*3*4);
    // aliases (lifetimes disjoint, sizes equal)
    float* lcf2    = lcf1;     // B*G2*C1 == B*G1*C0
    int*   ki2     = ki1;
    float* pooled2 = feats1;   // B*Co2*G2 == B*N1*C0

    // 1. transpose + zero acc
    k_transpose<<<(B*C0*N1 + 255)/256, 256, 0, stream>>>(x0, feats1, acc, B, C0, N1);

    // ---- stage 1 ----
    // 2. FPS (4 waves, NPT=16 packed as 8x vec2, DPP butterfly, fi in LDS)
    {
        size_t shm = (size_t)(2*4*8) + (size_t)G1*4 + (size_t)N1*16;
        k_fps_t<16, 4><<<B, 256, shm, stream>>>(xyz, fi1, N1, G1);
    }
    // 3. kNN + center gather
    k_knn<<<B*G1, 256, (size_t)(N1 + 32)*4, stream>>>(xyz, feats1, fi1, lcx1, lcf1, ki1,
                                                      B, N1, G1, C0, 0);
    // 4. fused std sums -> acc[0..3]
    k_stdsum<<<512, 256, 0, stream>>>(feats1, xyz, lcf1, lcx1, ki1, acc, B, N1, G1, C0);
    // 5. feature + pool (finalize inlined)
    {
        size_t shf = (size_t)(KNB*7 + KNB*3 + KNB + KNB*C0) * 4;
        k_feature<<<B*G1, 256, shf, stream>>>(xyz, feats1, lcx1, lcf1, ki1, B0, acc, pooled1,
                                              B, N1, G1, C0,
                                              (double)B*G1*KNB*C0, (double)B*G1*KNB*3);
    }
    // 6. BN + GELU (transposed -> feats layout for stage 2)
    k_bn<<<Co1, 256, 0, stream>>>(pooled1, g0, be0, feats2, B, Co1, G1, 1);

    // ---- stage 2 (xyz = lcx1, feats = feats2) ----
    // FPS on an FPS-ordered prefix set is the identity permutation (prefix-nesting;
    // exact incl. ties since selected points have dist 0 and any tied maximizer has
    // a later position). So centers are simply the first G2 points -> identity=1.
    // 7. kNN + identity center gather
    k_knn<<<B*G2, 256, (size_t)(N2 + 32)*4, stream>>>(lcx1, feats2, (const int*)nullptr,
                                                      lcx2, lcf2, ki2, B, N2, G2, C1, 1);
    // 8. fused std sums -> acc[4..7]
    k_stdsum<<<512, 256, 0, stream>>>(feats2, lcx1, lcf2, lcx2, ki2, acc + 4, B, N2, G2, C1);
    // 9. feature + pool
    {
        size_t shf = (size_t)(KNB*7 + KNB*3 + KNB + KNB*C1) * 4;
        k_feature<<<B*G2, 256, shf, stream>>>(lcx1, feats2, lcx2, lcf2, ki2, B1, acc + 4, pooled2,
                                              B, N2, G2, C1,
                                              (double)B*G2*KNB*C1, (double)B*G2*KNB*3);
    }
    // 10. BN + GELU -> final output
    k_bn<<<Co2, 256, 0, stream>>>(pooled2, g1, be1, out, B, Co2, G2, 0);
}